// Round 1
// baseline (261.728 us; speedup 1.0000x reference)
//
#include <hip/hip_runtime.h>
#include <stdint.h>

#define N_TOK 64
#define K_DIM 4096
#define N_OUT 11008
#define LUT_N 256
#define WIN 256      // K-columns per window (8 MFMA K-steps; wave w owns cols [w*64, w*64+64))

typedef __attribute__((ext_vector_type(4))) float  floatx4;
typedef __attribute__((ext_vector_type(8))) __bf16 bf16x8;

__device__ __forceinline__ unsigned bf16_rne(float f) {
  unsigned u = __builtin_bit_cast(unsigned, f);
  return (u + 0x7fffu + ((u >> 16) & 1u)) >> 16;  // round-nearest-even to bf16
}

// ---- pre-kernel: pack x (fp32 [64][4096]) into A-fragment-ordered bf16 ----
// chunk c = kstep*4 + tt, kstep in [0,128); lane (q,m15) holds 8 bf16:
//   x[(tt*16+m15)*4096 + kstep*32 + q*8 + j]
__global__ __launch_bounds__(256) void xpack_kernel(const float* __restrict__ x,
                                                    uint32_t* __restrict__ xp) {
  const int t = blockIdx.x * 256 + threadIdx.x;  // [0, 32768)
  const int lane = t & 63, c = t >> 6;
  const int m15 = lane & 15, q = lane >> 4;
  const int tt = c & 3, kstep = c >> 2;
  const int src = (tt * 16 + m15) * K_DIM + kstep * 32 + q * 8;
  float4 a = *(const float4*)(x + src);
  float4 b = *(const float4*)(x + src + 4);
  uint4 o;
  o.x = bf16_rne(a.x) | (bf16_rne(a.y) << 16);
  o.y = bf16_rne(a.z) | (bf16_rne(a.w) << 16);
  o.z = bf16_rne(b.x) | (bf16_rne(b.y) << 16);
  o.w = bf16_rne(b.z) | (bf16_rne(b.w) << 16);
  *(uint4*)(xp + (size_t)t * 4) = o;
}

// ---- main kernel ----
// Block = 16 output features, 4 waves. Barrier-free K-loop: wave w stages ONLY
// the 64 columns it consumes into a wave-private 4 KB slab (double-buffered),
// synchronizing on its own global_load_lds with counted s_waitcnt vmcnt(4) —
// loads for window n+1 stay in flight through compute of window n; vmcnt is
// never drained to 0 in the loop and there is NO __syncthreads per window.
//
// LDS slab is linear [16 rows][64 dwords] (global_load_lds writes linearly).
// Unswizzled, the ds_read_b128 readback (addr = m15*64 + s*32 + q*8) would be a
// 16-way bank conflict (bank = 8q). Both-sides XOR swizzle: data for (row r,
// col-dword u) lives at LDS dword r*64 + (u ^ ((r&7)<<2)). Staging achieves
// this by XORing the per-lane SOURCE 16B-granule index with r&7 (LDS dst stays
// linear); readback XORs the same swizzle -> uniform 8 accesses/bank (minimal).
//
// MFMA 16x16x32 bf16: A[m=lane&15][k=q*8+j], B[k=q*8+j][n=lane&15];
// C/D: row(token)=q*4+reg, col(feature)=lane&15.
__global__ __launch_bounds__(256, 3) void ghost_kernel(
    const int* __restrict__ gidx, const float* __restrict__ lut,
    const float* __restrict__ scale, const uint32_t* __restrict__ xp,
    float* __restrict__ out) {
  __shared__ uint32_t lut_lds[LUT_N * 16];     // 16 bank-strided LUT copies (16 KB)
  __shared__ uint32_t slab[4][2][16 * 64];     // per-wave double-buffered slabs (32 KB)

  const int tid = threadIdx.x;
  const int w = tid >> 6, lane = tid & 63;
  const int m15 = lane & 15, q = lane >> 4;
  const int blk = blockIdx.x;

  const int* grow = gidx + (size_t)blk * 16 * K_DIM;
  uint32_t* myslab = &slab[w][0][0];

  // stage window n into this wave's slab buffer (n&1).
  // call c covers rows c*4 + (lane>>4); lane's source granule is XOR-swizzled.
  auto load_win = [&](int n) {
    uint32_t* dst = myslab + (n & 1) * (16 * 64);
#pragma unroll
    for (int c = 0; c < 4; ++c) {
      const int r = c * 4 + (lane >> 4);
      const int colsw = ((lane & 15) ^ (r & 7)) << 2;  // pre-swizzled source
      const int* g = grow + (size_t)r * K_DIM + n * WIN + w * 64 + colsw;
      __builtin_amdgcn_global_load_lds(
          (const __attribute__((address_space(1))) void*)g,
          (__attribute__((address_space(3))) void*)(dst + c * 256), 16, 0, 0);
    }
  };

  load_win(0);  // issue first window before anything else (longest latency)

  {  // replicated LUT: copy c at dword [v*16+c]; lane uses copy lane&15
    unsigned hb = bf16_rne(lut[tid]);
#pragma unroll
    for (int c = 0; c < 16; ++c) lut_lds[tid * 16 + c] = hb;
  }

  floatx4 acc[4];
#pragma unroll
  for (int tt = 0; tt < 4; ++tt) acc[tt] = (floatx4){0.f, 0.f, 0.f, 0.f};

  const uint4* ap = (const uint4*)xp;

  __syncthreads();  // LUT visible to all waves (drains win0 too; prologue only)

  const int swz = (m15 & 7) << 2;

  for (int n = 0; n < 16; ++n) {
    if (n < 15) {
      load_win(n + 1);  // 4 loads stay in flight through compute of window n
      asm volatile("s_waitcnt vmcnt(4)" ::: "memory");  // window n arrived
    } else {
      asm volatile("s_waitcnt vmcnt(0)" ::: "memory");
    }
    __builtin_amdgcn_sched_barrier(0);

    const uint32_t* wb = myslab + (n & 1) * (16 * 64);
    const int kb = n * 8 + w * 2;  // global K-step base for this wave

#pragma unroll
    for (int s = 0; s < 2; ++s) {
      // A fragments (xp is L2-resident; latency hidden by LDS work below)
      uint4 a0 = ap[(size_t)((kb + s) * 4 + 0) * 64 + lane];
      uint4 a1 = ap[(size_t)((kb + s) * 4 + 1) * 64 + lane];
      uint4 a2 = ap[(size_t)((kb + s) * 4 + 2) * 64 + lane];
      uint4 a3 = ap[(size_t)((kb + s) * 4 + 3) * 64 + lane];

      // idx readback: 2x ds_read_b128 at XOR-swizzled addresses (8/bank uniform)
      const int off = s * 32 + q * 8;
      const uint4 iv0 = *(const uint4*)(wb + m15 * 64 + (off ^ swz));
      const uint4 iv1 = *(const uint4*)(wb + m15 * 64 + ((off + 4) ^ swz));

      // LUT gathers: dword addr v*16 + m15 -> <=2 lanes/bank typical (free)
      unsigned g0 = lut_lds[iv0.x * 16 + m15];
      unsigned g1 = lut_lds[iv0.y * 16 + m15];
      unsigned g2 = lut_lds[iv0.z * 16 + m15];
      unsigned g3 = lut_lds[iv0.w * 16 + m15];
      unsigned g4 = lut_lds[iv1.x * 16 + m15];
      unsigned g5 = lut_lds[iv1.y * 16 + m15];
      unsigned g6 = lut_lds[iv1.z * 16 + m15];
      unsigned g7 = lut_lds[iv1.w * 16 + m15];
      uint4 bi;
      bi.x = __builtin_amdgcn_perm(g1, g0, 0x05040100u);  // [bf16(k0)|bf16(k1)<<16]
      bi.y = __builtin_amdgcn_perm(g3, g2, 0x05040100u);
      bi.z = __builtin_amdgcn_perm(g5, g4, 0x05040100u);
      bi.w = __builtin_amdgcn_perm(g7, g6, 0x05040100u);
      const bf16x8 bfrag = __builtin_bit_cast(bf16x8, bi);

      acc[0] = __builtin_amdgcn_mfma_f32_16x16x32_bf16(
          __builtin_bit_cast(bf16x8, a0), bfrag, acc[0], 0, 0, 0);
      acc[1] = __builtin_amdgcn_mfma_f32_16x16x32_bf16(
          __builtin_bit_cast(bf16x8, a1), bfrag, acc[1], 0, 0, 0);
      acc[2] = __builtin_amdgcn_mfma_f32_16x16x32_bf16(
          __builtin_bit_cast(bf16x8, a2), bfrag, acc[2], 0, 0, 0);
      acc[3] = __builtin_amdgcn_mfma_f32_16x16x32_bf16(
          __builtin_bit_cast(bf16x8, a3), bfrag, acc[3], 0, 0, 0);
    }
  }

  // ---- cross-wave K reduction (reuse slab as scratch) + scale + store ----
  __syncthreads();
  floatx4* red = (floatx4*)&slab[0][0][0];  // 16 KB of the 32 KB slab region
#pragma unroll
  for (int tt = 0; tt < 4; ++tt) red[(w * 4 + tt) * 64 + lane] = acc[tt];
  __syncthreads();
  {
    floatx4 r = red[(0 * 4 + w) * 64 + lane];
    r += red[(1 * 4 + w) * 64 + lane];
    r += red[(2 * 4 + w) * 64 + lane];
    r += red[(3 * 4 + w) * 64 + lane];
    const float sc = scale[blk * 16 + m15];
    r *= sc;
#pragma unroll
    for (int i = 0; i < 4; ++i)
      out[(size_t)(16 * w + q * 4 + i) * N_OUT + blk * 16 + m15] = r[i];
  }
}

extern "C" void kernel_launch(void* const* d_in, const int* in_sizes, int n_in,
                              void* d_out, int out_size, void* d_ws, size_t ws_size,
                              hipStream_t stream) {
  const float* x   = (const float*)d_in[0];
  const int*   gi  = (const int*)d_in[1];
  const float* lut = (const float*)d_in[2];
  const float* sc  = (const float*)d_in[3];
  float*       out = (float*)d_out;

  uint32_t* xp = (uint32_t*)d_ws;  // 512 KB packed-A region
  xpack_kernel<<<(N_TOK * K_DIM / 8) / 256, 256, 0, stream>>>(x, xp);
  ghost_kernel<<<N_OUT / 16, 256, 0, stream>>>(gi, lut, sc, xp, out);
}

// Round 2
// 257.834 us; speedup vs baseline: 1.0151x; 1.0151x over previous
//
#include <hip/hip_runtime.h>
#include <stdint.h>

#define N_TOK 64
#define K_DIM 4096
#define N_OUT 11008
#define LUT_N 256
#define WIN 256      // K-columns per window (8 MFMA K-steps; wave w owns cols [w*64, w*64+64))

typedef __attribute__((ext_vector_type(4))) float  floatx4;
typedef __attribute__((ext_vector_type(8))) __bf16 bf16x8;

__device__ __forceinline__ unsigned bf16_rne(float f) {
  unsigned u = __builtin_bit_cast(unsigned, f);
  return (u + 0x7fffu + ((u >> 16) & 1u)) >> 16;  // round-nearest-even to bf16
}

// ---- pre-kernel: pack x (fp32 [64][4096]) into A-fragment-ordered bf16 ----
// chunk c = kstep*4 + tt, kstep in [0,128); lane (q,m15) holds 8 bf16:
//   x[(tt*16+m15)*4096 + kstep*32 + q*8 + j]
__global__ __launch_bounds__(256) void xpack_kernel(const float* __restrict__ x,
                                                    uint32_t* __restrict__ xp) {
  const int t = blockIdx.x * 256 + threadIdx.x;  // [0, 32768)
  const int lane = t & 63, c = t >> 6;
  const int m15 = lane & 15, q = lane >> 4;
  const int tt = c & 3, kstep = c >> 2;
  const int src = (tt * 16 + m15) * K_DIM + kstep * 32 + q * 8;
  float4 a = *(const float4*)(x + src);
  float4 b = *(const float4*)(x + src + 4);
  uint4 o;
  o.x = bf16_rne(a.x) | (bf16_rne(a.y) << 16);
  o.y = bf16_rne(a.z) | (bf16_rne(a.w) << 16);
  o.z = bf16_rne(b.x) | (bf16_rne(b.y) << 16);
  o.w = bf16_rne(b.z) | (bf16_rne(b.w) << 16);
  *(uint4*)(xp + (size_t)t * 4) = o;
}

// ---- main kernel ----
// Block = 16 output features, 4 waves. Barrier-free K-loop: wave w stages ONLY
// the 64 columns it consumes into a wave-private 4 KB slab (double-buffered).
//
// vmcnt is FIFO, so ISSUE ORDER is the contract (this round's fix):
//   per iter n:  [A_n x8 L2 loads] -> [win(n+1) x4 global_load_lds]
//                -> s_waitcnt vmcnt(12)   (waits ONLY win(n), the 4 oldest)
// The compiler's automatic wait before the MFMAs consumes a7 at vmcnt(4),
// which leaves win(n+1) in flight for a FULL iteration (~1000 cyc wall) —
// HBM latency is never exposed in the loop; vmcnt never drains to 0.
//
// LDS slab is linear [16 rows][64 dwords] (global_load_lds writes linearly).
// Unswizzled, the ds_read_b128 readback (addr = m15*64 + s*32 + q*8) would be a
// 16-way bank conflict. Both-sides XOR swizzle: data for (row r, col-dword u)
// lives at LDS dword r*64 + (u ^ ((r&7)<<2)); staging XORs the per-lane SOURCE
// 16B-granule index with r&7 (LDS dst stays linear); readback XORs the same
// swizzle -> uniform 8 accesses/bank (minimal for wave64 b128).
//
// MFMA 16x16x32 bf16: A[m=lane&15][k=q*8+j], B[k=q*8+j][n=lane&15];
// C/D: row(token)=q*4+reg, col(feature)=lane&15.
__global__ __launch_bounds__(256, 3) void ghost_kernel(
    const int* __restrict__ gidx, const float* __restrict__ lut,
    const float* __restrict__ scale, const uint32_t* __restrict__ xp,
    float* __restrict__ out) {
  __shared__ uint32_t lut_lds[LUT_N * 16];     // 16 bank-strided LUT copies (16 KB)
  __shared__ uint32_t slab[4][2][16 * 64];     // per-wave double-buffered slabs (32 KB)

  const int tid = threadIdx.x;
  const int w = tid >> 6, lane = tid & 63;
  const int m15 = lane & 15, q = lane >> 4;
  const int blk = blockIdx.x;

  const int* grow = gidx + (size_t)blk * 16 * K_DIM;
  uint32_t* myslab = &slab[w][0][0];

  // stage window n into this wave's slab buffer (n&1).
  // call c covers rows c*4 + (lane>>4); lane's source granule is XOR-swizzled.
  auto load_win = [&](int n) {
    uint32_t* dst = myslab + (n & 1) * (16 * 64);
#pragma unroll
    for (int c = 0; c < 4; ++c) {
      const int r = c * 4 + (lane >> 4);
      const int colsw = ((lane & 15) ^ (r & 7)) << 2;  // pre-swizzled source
      const int* g = grow + (size_t)r * K_DIM + n * WIN + w * 64 + colsw;
      __builtin_amdgcn_global_load_lds(
          (const __attribute__((address_space(1))) void*)g,
          (__attribute__((address_space(3))) void*)(dst + c * 256), 16, 0, 0);
    }
  };

  load_win(0);  // issue first window before anything else (longest latency)

  {  // replicated LUT: copy c at dword [v*16+c]; lane uses copy lane&15
    unsigned hb = bf16_rne(lut[tid]);
#pragma unroll
    for (int c = 0; c < 16; ++c) lut_lds[tid * 16 + c] = hb;
  }

  floatx4 acc[4];
#pragma unroll
  for (int tt = 0; tt < 4; ++tt) acc[tt] = (floatx4){0.f, 0.f, 0.f, 0.f};

  const uint4* ap = (const uint4*)xp;

  __syncthreads();  // LUT visible to all waves (drains win0 too; prologue only)

  const int swz = (m15 & 7) << 2;

  for (int n = 0; n < 16; ++n) {
    const int kb = n * 8 + w * 2;  // global K-step base for this wave

    // (1) A fragments for BOTH K-steps of this window, issued FIRST so they
    //     are older than the win(n+1) prefetch in the vmcnt FIFO.
    uint4 a[8];
#pragma unroll
    for (int s = 0; s < 2; ++s)
#pragma unroll
      for (int t = 0; t < 4; ++t)
        a[s * 4 + t] = ap[(size_t)((kb + s) * 4 + t) * 64 + lane];
    __builtin_amdgcn_sched_barrier(0);  // pin A-issue before the prefetch

    // (2) prefetch window n+1; (3) wait ONLY for window n (the 4 oldest).
    if (n < 15) {
      load_win(n + 1);
      asm volatile("s_waitcnt vmcnt(12)" ::: "memory");
    } else {
      asm volatile("s_waitcnt vmcnt(8)" ::: "memory");
    }
    __builtin_amdgcn_sched_barrier(0);  // no LDS read hoists above the wait

    const uint32_t* wb = myslab + (n & 1) * (16 * 64);

#pragma unroll
    for (int s = 0; s < 2; ++s) {
      // idx readback: 2x ds_read_b128 at XOR-swizzled addresses (8/bank uniform)
      const int off = s * 32 + q * 8;
      const uint4 iv0 = *(const uint4*)(wb + m15 * 64 + (off ^ swz));
      const uint4 iv1 = *(const uint4*)(wb + m15 * 64 + ((off + 4) ^ swz));

      // LUT gathers: dword addr v*16 + m15 -> <=2 lanes/bank typical (free)
      unsigned g0 = lut_lds[iv0.x * 16 + m15];
      unsigned g1 = lut_lds[iv0.y * 16 + m15];
      unsigned g2 = lut_lds[iv0.z * 16 + m15];
      unsigned g3 = lut_lds[iv0.w * 16 + m15];
      unsigned g4 = lut_lds[iv1.x * 16 + m15];
      unsigned g5 = lut_lds[iv1.y * 16 + m15];
      unsigned g6 = lut_lds[iv1.z * 16 + m15];
      unsigned g7 = lut_lds[iv1.w * 16 + m15];
      uint4 bi;
      bi.x = __builtin_amdgcn_perm(g1, g0, 0x05040100u);  // [bf16(k0)|bf16(k1)<<16]
      bi.y = __builtin_amdgcn_perm(g3, g2, 0x05040100u);
      bi.z = __builtin_amdgcn_perm(g5, g4, 0x05040100u);
      bi.w = __builtin_amdgcn_perm(g7, g6, 0x05040100u);
      const bf16x8 bfrag = __builtin_bit_cast(bf16x8, bi);

      acc[0] = __builtin_amdgcn_mfma_f32_16x16x32_bf16(
          __builtin_bit_cast(bf16x8, a[s * 4 + 0]), bfrag, acc[0], 0, 0, 0);
      acc[1] = __builtin_amdgcn_mfma_f32_16x16x32_bf16(
          __builtin_bit_cast(bf16x8, a[s * 4 + 1]), bfrag, acc[1], 0, 0, 0);
      acc[2] = __builtin_amdgcn_mfma_f32_16x16x32_bf16(
          __builtin_bit_cast(bf16x8, a[s * 4 + 2]), bfrag, acc[2], 0, 0, 0);
      acc[3] = __builtin_amdgcn_mfma_f32_16x16x32_bf16(
          __builtin_bit_cast(bf16x8, a[s * 4 + 3]), bfrag, acc[3], 0, 0, 0);
    }
  }

  // ---- cross-wave K reduction (reuse slab as scratch) + scale + store ----
  __syncthreads();
  floatx4* red = (floatx4*)&slab[0][0][0];  // 16 KB of the 32 KB slab region
#pragma unroll
  for (int tt = 0; tt < 4; ++tt) red[(w * 4 + tt) * 64 + lane] = acc[tt];
  __syncthreads();
  {
    floatx4 r = red[(0 * 4 + w) * 64 + lane];
    r += red[(1 * 4 + w) * 64 + lane];
    r += red[(2 * 4 + w) * 64 + lane];
    r += red[(3 * 4 + w) * 64 + lane];
    const float sc = scale[blk * 16 + m15];
    r *= sc;
#pragma unroll
    for (int i = 0; i < 4; ++i)
      out[(size_t)(16 * w + q * 4 + i) * N_OUT + blk * 16 + m15] = r[i];
  }
}

extern "C" void kernel_launch(void* const* d_in, const int* in_sizes, int n_in,
                              void* d_out, int out_size, void* d_ws, size_t ws_size,
                              hipStream_t stream) {
  const float* x   = (const float*)d_in[0];
  const int*   gi  = (const int*)d_in[1];
  const float* lut = (const float*)d_in[2];
  const float* sc  = (const float*)d_in[3];
  float*       out = (float*)d_out;

  uint32_t* xp = (uint32_t*)d_ws;  // 512 KB packed-A region
  xpack_kernel<<<(N_TOK * K_DIM / 8) / 256, 256, 0, stream>>>(x, xp);
  ghost_kernel<<<N_OUT / 16, 256, 0, stream>>>(gi, lut, sc, xp, out);
}